// Round 2
// baseline (50.401 us; speedup 1.0000x reference)
//
#include <hip/hip_runtime.h>

#define BB 16
#define CC 64
#define HH 64
#define WW 64
#define OO 128

// Block: 256 threads = 4 rows x 64 cols (one wave per image row).
// Grid: 2048 blocks = 8 o-chunks * 256 regions (region = b*16 + hstrip).
// bid = ochunk*256 + region  =>  XCD = bid % 8 = region % 8, so all 8
// o-chunks reading the same x region land on the SAME XCD's L2 (~3 MB
// working set per XCD, fits 4 MB L2).
__global__ __launch_bounds__(256) void minimax_conv_kernel(
    const float* __restrict__ x, const float* __restrict__ w1,
    const float* __restrict__ w2, const int* __restrict__ conn,
    float* __restrict__ out)
{
    const int tid  = threadIdx.x;
    const int w    = tid & 63;        // lane -> column (coalesced)
    const int hloc = tid >> 6;        // wave id within block -> row
    const int bid = blockIdx.x;
    const int ochunk = bid >> 8;      // 0..7 : 16 output channels each
    const int region = bid & 255;
    const int b  = region >> 4;
    const int h0 = (region & 15) * 4;
    const int h  = h0 + hloc;
    // force wave-uniform row into SGPR so tap addresses stay scalar
    const int hs = __builtin_amdgcn_readfirstlane(h);

    // per-lane clamped columns for j-1 in {-1, 0, +1}  (edge-replicate pad)
    const int colm = (w == 0)  ? 0  : (w - 1);
    const int colp = (w == 63) ? 63 : (w + 1);

    const float* xb = x + (size_t)b * (CC * HH * WW);

    #pragma unroll 2
    for (int oi = 0; oi < 16; ++oi) {
        const int o = ochunk * 16 + oi;

        float d[9];
        #pragma unroll
        for (int t = 0; t < 9; ++t) {
            const int v = conn[o * 9 + t];     // wave-uniform -> s_load
            const int c = v / 9;
            const int r = v - c * 9;
            const int i = r / 3;               // 0..2 kernel row
            const int j = r - i * 3;           // 0..2 kernel col
            int row = hs + i - 1;
            row = row < 0 ? 0 : (row > HH - 1 ? HH - 1 : row);
            const int col = (j == 0) ? colm : ((j == 1) ? w : colp);
            const float g = xb[(c * HH + row) * WW + col];  // coalesced per wave
            d[t] = fabsf(g - w1[o * 9 + t]);
        }
        const float e0 = fmaxf(fmaxf(d[0], d[1]), d[2]);
        const float e1 = fmaxf(fmaxf(d[3], d[4]), d[5]);
        const float e2 = fmaxf(fmaxf(d[6], d[7]), d[8]);
        const float m0 = fabsf(e0 - w2[o * 3 + 0]);
        const float m1 = fabsf(e1 - w2[o * 3 + 1]);
        const float m2 = fabsf(e2 - w2[o * 3 + 2]);
        const float res = fminf(fminf(m0, m1), m2);

        out[(((size_t)b * OO + o) * HH + h) * WW + w] = res;
    }
}

extern "C" void kernel_launch(void* const* d_in, const int* in_sizes, int n_in,
                              void* d_out, int out_size, void* d_ws, size_t ws_size,
                              hipStream_t stream) {
    const float* x    = (const float*)d_in[0];
    const float* w1   = (const float*)d_in[1];
    const float* w2   = (const float*)d_in[2];
    const int*   conn = (const int*)d_in[3];
    float* out = (float*)d_out;

    const int blocks = 8 * 256;   // o-chunks * regions = 2048
    minimax_conv_kernel<<<blocks, 256, 0, stream>>>(x, w1, w2, conn, out);
}

// Round 3
// 29.796 us; speedup vs baseline: 1.6915x; 1.6915x over previous
//
#include <hip/hip_runtime.h>

#define BB 16
#define CC 64
#define HH 64
#define WW 64
#define OO 128

// lane L (0..15 within a row) gets src from lane L-1; first lane of each
// 16-lane DPP row keeps `edge` (replicate-pad clamp).
__device__ __forceinline__ float dpp_shr1(float src, float edge) {
    int old = __builtin_bit_cast(int, edge);
    int s   = __builtin_bit_cast(int, src);
    int r = __builtin_amdgcn_update_dpp(old, s, 0x111, 0xF, 0xF, false); // row_shr:1
    return __builtin_bit_cast(float, r);
}
// lane L gets src from lane L+1; last lane of each 16-lane row keeps `edge`.
__device__ __forceinline__ float dpp_shl1(float src, float edge) {
    int old = __builtin_bit_cast(int, edge);
    int s   = __builtin_bit_cast(int, src);
    int r = __builtin_amdgcn_update_dpp(old, s, 0x101, 0xF, 0xF, false); // row_shl:1
    return __builtin_bit_cast(float, r);
}

// Block: 256 threads = 16 image rows x 16 lanes; each lane owns 4 consecutive
// columns (cols 4L..4L+3) -> one float4 load per tap serves 4 outputs.
// Grid: 2048 = 32 o-chunks (4 o each) * 64 regions (b * 4 row-strips of 16).
// bid = ochunk*64 + region => XCD = region % 8 (all o-chunks of a region share L2).
__global__ __launch_bounds__(256) void minimax_conv_kernel(
    const float* __restrict__ x, const float* __restrict__ w1,
    const float* __restrict__ w2, const int* __restrict__ conn,
    float* __restrict__ out)
{
    const int tid  = threadIdx.x;
    const int L    = tid & 15;        // column group within row
    const int hrow = tid >> 4;        // 0..15 row within block
    const int bid = blockIdx.x;
    const int ochunk = bid >> 6;      // 0..31 : 4 output channels each
    const int region = bid & 63;
    const int b  = region >> 2;
    const int h0 = (region & 3) * 16;
    const int h  = h0 + hrow;

    // per-lane clamped row offsets (elements) for kernel row i = 0,1,2
    int rowoff[3];
    #pragma unroll
    for (int i = 0; i < 3; ++i) {
        int r = h + i - 1;
        r = r < 0 ? 0 : (r > HH - 1 ? HH - 1 : r);
        rowoff[i] = r * WW + 4 * L;
    }

    const float* xb = x + (size_t)b * (CC * HH * WW);

    #pragma unroll
    for (int oi = 0; oi < 4; ++oi) {
        const int o = ochunk * 4 + oi;

        float res0, res1, res2, res3;
        #pragma unroll
        for (int p = 0; p < 3; ++p) {          // branch
            float e0, e1, e2, e3;
            #pragma unroll
            for (int tt = 0; tt < 3; ++tt) {   // tap within branch
                const int t = p * 3 + tt;
                const int v = conn[o * 9 + t];         // wave-uniform (s_load)
                const int c = v / 9;
                const int r = v - c * 9;
                const int i = r / 3;                   // kernel row
                const int j = r - i * 3;               // kernel col
                const float w1v = w1[o * 9 + t];       // uniform

                const float4 q = *(const float4*)(xb + (size_t)c * (HH * WW) + rowoff[i]);

                float v0, v1, v2, v3;
                if (j == 0) {                          // uniform branch
                    const float le = dpp_shr1(q.w, q.x);
                    v0 = le;  v1 = q.x; v2 = q.y; v3 = q.z;
                } else if (j == 1) {
                    v0 = q.x; v1 = q.y; v2 = q.z; v3 = q.w;
                } else {
                    const float re = dpp_shl1(q.x, q.w);
                    v0 = q.y; v1 = q.z; v2 = q.w; v3 = re;
                }
                const float d0 = fabsf(v0 - w1v);
                const float d1 = fabsf(v1 - w1v);
                const float d2 = fabsf(v2 - w1v);
                const float d3 = fabsf(v3 - w1v);
                if (tt == 0) { e0 = d0; e1 = d1; e2 = d2; e3 = d3; }
                else {
                    e0 = fmaxf(e0, d0); e1 = fmaxf(e1, d1);
                    e2 = fmaxf(e2, d2); e3 = fmaxf(e3, d3);
                }
            }
            const float w2v = w2[o * 3 + p];           // uniform
            const float m0 = fabsf(e0 - w2v);
            const float m1 = fabsf(e1 - w2v);
            const float m2 = fabsf(e2 - w2v);
            const float m3 = fabsf(e3 - w2v);
            if (p == 0) { res0 = m0; res1 = m1; res2 = m2; res3 = m3; }
            else {
                res0 = fminf(res0, m0); res1 = fminf(res1, m1);
                res2 = fminf(res2, m2); res3 = fminf(res3, m3);
            }
        }

        float4 outv; outv.x = res0; outv.y = res1; outv.z = res2; outv.w = res3;
        *(float4*)(out + ((((size_t)b * OO + o) * HH + h) * WW + 4 * L)) = outv;
    }
}

extern "C" void kernel_launch(void* const* d_in, const int* in_sizes, int n_in,
                              void* d_out, int out_size, void* d_ws, size_t ws_size,
                              hipStream_t stream) {
    const float* x    = (const float*)d_in[0];
    const float* w1   = (const float*)d_in[1];
    const float* w2   = (const float*)d_in[2];
    const int*   conn = (const int*)d_in[3];
    float* out = (float*)d_out;

    const int blocks = 32 * 64;   // o-chunks * regions = 2048
    minimax_conv_kernel<<<blocks, 256, 0, stream>>>(x, w1, w2, conn, out);
}